// Round 3
// baseline (763.639 us; speedup 1.0000x reference)
//
#include <hip/hip_runtime.h>

#define B_ 4
#define L_ 2000
#define LP 2048       // padded length for Q/K/V buffers
#define C_ 512
#define H_ 8
#define HD 64
#define CHUNK_ 1000

typedef __attribute__((ext_vector_type(8))) short bf16x8;
typedef __attribute__((ext_vector_type(4))) float f32x4;

__device__ inline unsigned short f2bf(float f) {
    union { float f; unsigned int u; } v; v.f = f;
    unsigned int r = v.u + 0x7fffu + ((v.u >> 16) & 1u);
    return (unsigned short)(r >> 16);
}

// -------------------------------------------------------------------------
// conv (depthwise k=3, zero pad at 1000-chunk boundaries) + residual + bias,
// bf16 out; also emits x cast to bf16.
// -------------------------------------------------------------------------
__global__ void conv_kernel(const float* __restrict__ x, const float* __restrict__ Wl,
                            const float* __restrict__ bl,
                            unsigned short* __restrict__ kv16,
                            unsigned short* __restrict__ x16) {
    int idx = blockIdx.x * 256 + threadIdx.x;
    if (idx >= B_ * L_ * C_) return;
    int c = idx & (C_ - 1);
    int l = (idx / C_) % L_;
    int p = l % CHUNK_;
    float xc = x[idx];
    float left  = (p > 0)          ? x[idx - C_] : 0.f;
    float right = (p < CHUNK_ - 1) ? x[idx + C_] : 0.f;
    float y = xc + bl[c] + Wl[c * 3 + 0] * left + Wl[c * 3 + 1] * xc + Wl[c * 3 + 2] * right;
    kv16[idx] = f2bf(y);
    x16[idx]  = f2bf(xc);
}

__global__ void cvt_kernel(const float* __restrict__ src,
                           unsigned short* __restrict__ dst, int n) {
    int i = blockIdx.x * 256 + threadIdx.x;
    if (i < n) dst[i] = f2bf(src[i]);
}

// -------------------------------------------------------------------------
// Projection GEMM via MFMA, LDS-staged coalesced epilogue.
// A:[8000][512] bf16, W:[N][512] bf16. Block: 4 waves, 64m x 64n tile.
// mode 0: Q -> [bh][2048][64]. mode 1: by<8 -> K [bh][2048][64];
//         by>=8 -> V transposed [bh][64][2048] (LDS transpose, row stores).
// -------------------------------------------------------------------------
__global__ __launch_bounds__(256) void proj_mfma(
    const unsigned short* __restrict__ A, const unsigned short* __restrict__ W,
    const float* __restrict__ bias,
    unsigned short* __restrict__ o0, unsigned short* __restrict__ o1, int mode) {
    __shared__ __align__(16) unsigned short tile[64][72];
    const int tid = threadIdx.x;
    const int lane = tid & 63;
    const int wave = tid >> 6;
    const int c = lane & 15;
    const int quad = lane >> 4;
    const int mrow = blockIdx.x * 64 + wave * 16 + c;
    const int n0 = blockIdx.y * 64;
    f32x4 acc[4] = {{0,0,0,0},{0,0,0,0},{0,0,0,0},{0,0,0,0}};
    const unsigned short* Ap = A + (size_t)mrow * C_ + quad * 8;
#pragma unroll 4
    for (int k0 = 0; k0 < C_; k0 += 32) {
        bf16x8 a = *(const bf16x8*)(Ap + k0);
#pragma unroll
        for (int t = 0; t < 4; t++) {
            bf16x8 wv = *(const bf16x8*)&W[(size_t)(n0 + 16 * t + c) * C_ + k0 + quad * 8];
            acc[t] = __builtin_amdgcn_mfma_f32_16x16x32_bf16(a, wv, acc[t], 0, 0, 0);
        }
    }
    const bool vpath = (mode == 1 && n0 >= C_);
    const int lm = wave * 16 + quad * 4;
#pragma unroll
    for (int t = 0; t < 4; t++) {
        float bv = bias[n0 + 16 * t + c];
#pragma unroll
        for (int r = 0; r < 4; r++) {
            unsigned short val = f2bf(acc[t][r] + bv);
            if (!vpath) tile[lm + r][16 * t + c] = val;   // [m][n]
            else        tile[16 * t + c][lm + r] = val;   // [n][m] transpose
        }
    }
    __syncthreads();
    if (!vpath) {
        int lr = tid >> 2, chunk = (tid & 3) * 16;
        int m = blockIdx.x * 64 + lr;
        int b = m / L_, l = m % L_;
        int nn = (n0 + chunk) & (C_ - 1);
        int h = nn >> 6, d0 = nn & 63;
        unsigned short* dst = &o0[(((size_t)(b * H_ + h) * LP) + l) * HD + d0];
        *(uint4*)dst       = *(const uint4*)&tile[lr][chunk];
        *(uint4*)(dst + 8) = *(const uint4*)&tile[lr][chunk + 8];
    } else {
        int dr = tid >> 2, chunk = (tid & 3) * 16;
        int nn = (n0 - C_) + dr;
        int h = nn >> 6, d = nn & 63;
        int mbase = blockIdx.x * 64 + chunk;
        int b0 = mbase / L_, b1 = (mbase + 15) / L_;
        if (b0 == b1) {
            int l = mbase % L_;
            unsigned short* dst = &o1[(((size_t)(b0 * H_ + h) * HD) + d) * LP + l];
            *(uint4*)dst       = *(const uint4*)&tile[dr][chunk];
            *(uint4*)(dst + 8) = *(const uint4*)&tile[dr][chunk + 8];
        } else {
            for (int i = 0; i < 16; i++) {
                int m = mbase + i;
                int b = m / L_, l = m % L_;
                o1[(((size_t)(b * H_ + h) * HD) + d) * LP + l] = tile[dr][chunk + i];
            }
        }
    }
}

// -------------------------------------------------------------------------
// Flash attention, bf16 MFMA, split-K x2 (additive merge: no running max).
// grid 2048: bid = b(2) | ks(1) | h(3) | rt(5), b fastest for rpe L3 reuse.
// Partials: po[ks][bh][l][d] fp32 (coalesced), lsum[ks][bh][2048].
// VGPR<=64 forced for 8 waves/SIMD.
// -------------------------------------------------------------------------
__global__ __launch_bounds__(256, 8) void attn_mfma(
    const unsigned short* __restrict__ Q, const unsigned short* __restrict__ K,
    const unsigned short* __restrict__ Vt, const float* __restrict__ rpe,
    float* __restrict__ po, float* __restrict__ lsum) {
    __shared__ __align__(16) unsigned short Ps[4][16][72];
    const int lane = threadIdx.x & 63;
    const int wave = threadIdx.x >> 6;
    const int c = lane & 15;
    const int quad = lane >> 4;
    const int bid = blockIdx.x;
    const int b  = bid & 3;
    const int ks = (bid >> 2) & 1;
    const int h  = (bid >> 3) & 7;
    const int rt = bid >> 6;
    const int r0 = rt * 64 + wave * 16;
    const int bh = b * H_ + h;
    const unsigned short* Qb = Q + (size_t)bh * LP * HD;
    const unsigned short* Kb = K + (size_t)bh * LP * HD;
    const unsigned short* Vb = Vt + (size_t)bh * HD * LP;
    const float* rb = rpe + (size_t)h * L_ * L_;

    bf16x8 qf0 = *(const bf16x8*)&Qb[(size_t)(r0 + c) * HD + quad * 8];
    bf16x8 qf1 = *(const bf16x8*)&Qb[(size_t)(r0 + c) * HD + 32 + quad * 8];

    float l_i[4] = {0.f, 0.f, 0.f, 0.f};
    f32x4 o_acc[4] = {{0,0,0,0},{0,0,0,0},{0,0,0,0},{0,0,0,0}};
    const int rg0 = r0 + quad * 4;

    const int kt_end = ks * 16 + 16;
    for (int kt = ks * 16; kt < kt_end; kt++) {
        const int c0 = kt * 64;
        // ---- S = Q K^T ----
        f32x4 s[4];
#pragma unroll
        for (int t = 0; t < 4; t++) {
            const unsigned short* kp = &Kb[(size_t)(c0 + 16 * t + c) * HD + quad * 8];
            bf16x8 k0f = *(const bf16x8*)kp;
            bf16x8 k1f = *(const bf16x8*)(kp + 32);
            f32x4 z = {0, 0, 0, 0};
            z = __builtin_amdgcn_mfma_f32_16x16x32_bf16(qf0, k0f, z, 0, 0, 0);
            z = __builtin_amdgcn_mfma_f32_16x16x32_bf16(qf1, k1f, z, 0, 0, 0);
            s[t] = z;
        }
        // ---- scale + rpe + exp; lane-local l_i; P -> LDS ----
        if (c0 + 64 <= L_) {          // fast path: no column mask needed
#pragma unroll
            for (int r = 0; r < 4; r++) {
                const int rg = rg0 + r;
                const bool rok = rg < L_;
                const float* rrow = rb + (size_t)rg * L_ + c0 + c;
                float ps = 0.f;
#pragma unroll
                for (int t = 0; t < 4; t++) {
                    float xv = s[t][r] * 0.125f + (rok ? rrow[16 * t] : 0.f);
                    float p = __expf(xv);
                    ps += p;
                    Ps[wave][quad * 4 + r][16 * t + c] = f2bf(p);
                }
                l_i[r] += ps;
            }
        } else {                      // last tile: mask cols >= L
#pragma unroll
            for (int r = 0; r < 4; r++) {
                const int rg = rg0 + r;
                const bool rok = rg < L_;
                const float* rrow = rb + (size_t)rg * L_ + c0 + c;
                float ps = 0.f;
#pragma unroll
                for (int t = 0; t < 4; t++) {
                    int col = c0 + 16 * t + c;
                    float xv = (col < L_)
                        ? s[t][r] * 0.125f + (rok ? rrow[16 * t] : 0.f)
                        : -1e30f;
                    float p = __expf(xv);
                    ps += p;
                    Ps[wave][quad * 4 + r][16 * t + c] = f2bf(p);
                }
                l_i[r] += ps;
            }
        }
        // ---- O += P V ----
        bf16x8 pa0 = *(const bf16x8*)&Ps[wave][c][quad * 8];
        bf16x8 pa1 = *(const bf16x8*)&Ps[wave][c][32 + quad * 8];
#pragma unroll
        for (int t = 0; t < 4; t++) {
            const unsigned short* vp = &Vb[(size_t)(16 * t + c) * LP + c0 + quad * 8];
            bf16x8 v0 = *(const bf16x8*)vp;
            bf16x8 v1 = *(const bf16x8*)(vp + 32);
            o_acc[t] = __builtin_amdgcn_mfma_f32_16x16x32_bf16(pa0, v0, o_acc[t], 0, 0, 0);
            o_acc[t] = __builtin_amdgcn_mfma_f32_16x16x32_bf16(pa1, v1, o_acc[t], 0, 0, 0);
        }
    }
    // ---- epilogue: reduce l over the 16 c-lanes; store partials ----
#pragma unroll
    for (int r = 0; r < 4; r++) {
        float v = l_i[r];
        v += __shfl_xor(v, 1);
        v += __shfl_xor(v, 2);
        v += __shfl_xor(v, 4);
        v += __shfl_xor(v, 8);
        l_i[r] = v;
    }
    float* pob = po + (size_t)(ks * 32 + bh) * L_ * HD;
#pragma unroll
    for (int t = 0; t < 4; t++) {
        int d = 16 * t + c;
#pragma unroll
        for (int r = 0; r < 4; r++) {
            int l = rg0 + r;
            if (l < L_) pob[(size_t)l * HD + d] = o_acc[t][r];
        }
    }
    if (c == 0) {
        float* lb = lsum + (size_t)(ks * 32 + bh) * LP;
#pragma unroll
        for (int r = 0; r < 4; r++) lb[rg0 + r] = l_i[r];
    }
}

// -------------------------------------------------------------------------
// Merge: out[bh][d][l] = (po0+po1)[bh][l][d] / (l0+l1)[bh][l], LDS transpose.
// grid: 32 bh x 32 l-tiles.
// -------------------------------------------------------------------------
__global__ __launch_bounds__(256) void merge_kernel(
    const float* __restrict__ po, const float* __restrict__ lsum,
    float* __restrict__ out) {
    __shared__ __align__(16) float T[64][68];
    const int tid = threadIdx.x;
    const int bh = blockIdx.x >> 5;
    const int lt = blockIdx.x & 31;
    const float* p0 = po + (size_t)bh * L_ * HD;
    const float* p1 = p0 + (size_t)32 * L_ * HD;
    const float* ls0 = lsum + (size_t)bh * LP;
    const float* ls1 = ls0 + (size_t)32 * LP;
#pragma unroll
    for (int it = 0; it < 4; it++) {
        int idx = it * 256 + tid;
        int row = idx >> 4;
        int dc = (idx & 15) * 4;
        int l = lt * 64 + row;
        float4 v = make_float4(0.f, 0.f, 0.f, 0.f);
        if (l < L_) {
            float4 a  = *(const float4*)&p0[(size_t)l * HD + dc];
            float4 b4 = *(const float4*)&p1[(size_t)l * HD + dc];
            float inv = 1.f / (ls0[l] + ls1[l]);
            v = make_float4((a.x + b4.x) * inv, (a.y + b4.y) * inv,
                            (a.z + b4.z) * inv, (a.w + b4.w) * inv);
        }
        T[dc + 0][row] = v.x; T[dc + 1][row] = v.y;
        T[dc + 2][row] = v.z; T[dc + 3][row] = v.w;
    }
    __syncthreads();
    const int d = tid >> 2, ch = (tid & 3) * 16;
    const int lbase = lt * 64 + ch;
    if (lbase + 15 < L_) {
        float* dst = &out[((size_t)(bh * HD + d)) * L_ + lbase];
#pragma unroll
        for (int i = 0; i < 4; i++)
            *(float4*)&dst[4 * i] = *(const float4*)&T[d][ch + 4 * i];
    }
}

extern "C" void kernel_launch(void* const* d_in, const int* in_sizes, int n_in,
                              void* d_out, int out_size, void* d_ws, size_t ws_size,
                              hipStream_t stream) {
    const float* x   = (const float*)d_in[0];
    const float* rpe = (const float*)d_in[1];
    const float* Wq  = (const float*)d_in[2];
    const float* bq  = (const float*)d_in[3];
    const float* Wkv = (const float*)d_in[4];
    const float* bkv = (const float*)d_in[5];
    const float* Wl  = (const float*)d_in[6];
    const float* bl  = (const float*)d_in[7];
    float* out = (float*)d_out;

    // ws layout: ushort section (43.1 MB) then float section (33.3 MB)
    unsigned short* wsu  = (unsigned short*)d_ws;
    unsigned short* x16  = wsu;                 // 4,096,000
    unsigned short* kv16 = wsu + 4096000;       // 4,096,000
    unsigned short* Wq16 = wsu + 8192000;       //   262,144
    unsigned short* Wkv16= wsu + 8454144;       //   524,288
    unsigned short* Q16  = wsu + 8978432;       // 4,194,304  [bh][2048][64]
    unsigned short* K16  = wsu + 13172736;      // 4,194,304  [bh][2048][64]
    unsigned short* V16  = wsu + 17367040;      // 4,194,304  [bh][64][2048]
    float* po   = (float*)(wsu + 21561344);     // 8,192,000 fp32 [2][32][2000][64]
    float* lsum = po + 8192000;                 //   131,072 fp32 [2][32][2048]

    const int total = B_ * L_ * C_;
    conv_kernel<<<(total + 255) / 256, 256, 0, stream>>>(x, Wl, bl, kv16, x16);
    cvt_kernel<<<262144 / 256, 256, 0, stream>>>(Wq, Wq16, 262144);
    cvt_kernel<<<524288 / 256, 256, 0, stream>>>(Wkv, Wkv16, 524288);
    proj_mfma<<<dim3(125, 8), 256, 0, stream>>>(x16, Wq16, bq, Q16, nullptr, 0);
    proj_mfma<<<dim3(125, 16), 256, 0, stream>>>(kv16, Wkv16, bkv, K16, V16, 1);
    attn_mfma<<<2048, 256, 0, stream>>>(Q16, K16, V16, rpe, po, lsum);
    merge_kernel<<<1024, 256, 0, stream>>>(po, lsum, out);
}

// Round 4
// 619.503 us; speedup vs baseline: 1.2327x; 1.2327x over previous
//
#include <hip/hip_runtime.h>

#define B_ 4
#define L_ 2000
#define LP 2048       // padded length for Q/K/V buffers
#define C_ 512
#define H_ 8
#define HD 64
#define CHUNK_ 1000

typedef __attribute__((ext_vector_type(8))) short bf16x8;
typedef __attribute__((ext_vector_type(4))) float f32x4;

__device__ inline unsigned short f2bf(float f) {
    union { float f; unsigned int u; } v; v.f = f;
    unsigned int r = v.u + 0x7fffu + ((v.u >> 16) & 1u);
    return (unsigned short)(r >> 16);
}

// -------------------------------------------------------------------------
// conv (depthwise k=3, zero pad at 1000-chunk boundaries) + residual + bias,
// bf16 out; also emits x cast to bf16. Vectorized x4 over channels.
// -------------------------------------------------------------------------
__global__ void conv_kernel(const float* __restrict__ x, const float* __restrict__ Wl,
                            const float* __restrict__ bl,
                            unsigned short* __restrict__ kv16,
                            unsigned short* __restrict__ x16) {
    int i4 = blockIdx.x * 256 + threadIdx.x;
    if (i4 >= B_ * L_ * C_ / 4) return;
    int idx = i4 * 4;
    int c = idx & (C_ - 1);
    int l = (idx >> 9) % L_;
    int p = l % CHUNK_;
    float4 xc = *(const float4*)&x[idx];
    float4 lf = (p > 0)          ? *(const float4*)&x[idx - C_] : make_float4(0, 0, 0, 0);
    float4 rt = (p < CHUNK_ - 1) ? *(const float4*)&x[idx + C_] : make_float4(0, 0, 0, 0);
    float y[4];
    const float* xcp = &xc.x; const float* lfp = &lf.x; const float* rtp = &rt.x;
#pragma unroll
    for (int j = 0; j < 4; j++) {
        y[j] = xcp[j] + bl[c + j] + Wl[(c + j) * 3 + 0] * lfp[j]
             + Wl[(c + j) * 3 + 1] * xcp[j] + Wl[(c + j) * 3 + 2] * rtp[j];
    }
    ushort4 kv = make_ushort4(f2bf(y[0]), f2bf(y[1]), f2bf(y[2]), f2bf(y[3]));
    ushort4 xo = make_ushort4(f2bf(xcp[0]), f2bf(xcp[1]), f2bf(xcp[2]), f2bf(xcp[3]));
    *(ushort4*)&kv16[idx] = kv;
    *(ushort4*)&x16[idx]  = xo;
}

// Both weight tensors cast in one launch (x4 vectorized).
__global__ void cvt_kernel(const float* __restrict__ Wq, const float* __restrict__ Wkv,
                           unsigned short* __restrict__ Wq16,
                           unsigned short* __restrict__ Wkv16) {
    int i4 = blockIdx.x * 256 + threadIdx.x;
    int idx = i4 * 4;
    const float* src; unsigned short* dst; int off;
    if (idx < 262144) { src = Wq; dst = Wq16; off = idx; }
    else if (idx < 786432) { src = Wkv; dst = Wkv16; off = idx - 262144; }
    else return;
    float4 v = *(const float4*)&src[off];
    *(ushort4*)&dst[off] = make_ushort4(f2bf(v.x), f2bf(v.y), f2bf(v.z), f2bf(v.w));
}

// -------------------------------------------------------------------------
// Projection GEMM via MFMA, LDS-staged coalesced epilogue.
// A:[8000][512] bf16, W:[N][512] bf16. Block: 4 waves, 64m x 64n tile.
// mode 0: Q -> [bh][2048][64]. mode 1: by<8 -> K [bh][2048][64];
//         by>=8 -> V transposed [bh][64][2048] (LDS transpose, row stores).
// -------------------------------------------------------------------------
__global__ __launch_bounds__(256) void proj_mfma(
    const unsigned short* __restrict__ A, const unsigned short* __restrict__ W,
    const float* __restrict__ bias,
    unsigned short* __restrict__ o0, unsigned short* __restrict__ o1, int mode) {
    __shared__ __align__(16) unsigned short tile[64][72];
    const int tid = threadIdx.x;
    const int lane = tid & 63;
    const int wave = tid >> 6;
    const int c = lane & 15;
    const int quad = lane >> 4;
    const int mrow = blockIdx.x * 64 + wave * 16 + c;
    const int n0 = blockIdx.y * 64;
    f32x4 acc[4] = {{0,0,0,0},{0,0,0,0},{0,0,0,0},{0,0,0,0}};
    const unsigned short* Ap = A + (size_t)mrow * C_ + quad * 8;
#pragma unroll 4
    for (int k0 = 0; k0 < C_; k0 += 32) {
        bf16x8 a = *(const bf16x8*)(Ap + k0);
#pragma unroll
        for (int t = 0; t < 4; t++) {
            bf16x8 wv = *(const bf16x8*)&W[(size_t)(n0 + 16 * t + c) * C_ + k0 + quad * 8];
            acc[t] = __builtin_amdgcn_mfma_f32_16x16x32_bf16(a, wv, acc[t], 0, 0, 0);
        }
    }
    const bool vpath = (mode == 1 && n0 >= C_);
    const int lm = wave * 16 + quad * 4;
#pragma unroll
    for (int t = 0; t < 4; t++) {
        float bv = bias[n0 + 16 * t + c];
#pragma unroll
        for (int r = 0; r < 4; r++) {
            unsigned short val = f2bf(acc[t][r] + bv);
            if (!vpath) tile[lm + r][16 * t + c] = val;   // [m][n]
            else        tile[16 * t + c][lm + r] = val;   // [n][m] transpose
        }
    }
    __syncthreads();
    if (!vpath) {
        int lr = tid >> 2, chunk = (tid & 3) * 16;
        int m = blockIdx.x * 64 + lr;
        int b = m / L_, l = m % L_;
        int nn = (n0 + chunk) & (C_ - 1);
        int h = nn >> 6, d0 = nn & 63;
        unsigned short* dst = &o0[(((size_t)(b * H_ + h) * LP) + l) * HD + d0];
        *(uint4*)dst       = *(const uint4*)&tile[lr][chunk];
        *(uint4*)(dst + 8) = *(const uint4*)&tile[lr][chunk + 8];
    } else {
        int dr = tid >> 2, chunk = (tid & 3) * 16;
        int nn = (n0 - C_) + dr;
        int h = nn >> 6, d = nn & 63;
        int mbase = blockIdx.x * 64 + chunk;
        int b0 = mbase / L_, b1 = (mbase + 15) / L_;
        if (b0 == b1) {
            int l = mbase % L_;
            unsigned short* dst = &o1[(((size_t)(b0 * H_ + h) * HD) + d) * LP + l];
            *(uint4*)dst       = *(const uint4*)&tile[dr][chunk];
            *(uint4*)(dst + 8) = *(const uint4*)&tile[dr][chunk + 8];
        } else {
            for (int i = 0; i < 16; i++) {
                int m = mbase + i;
                int b = m / L_, l = m % L_;
                o1[(((size_t)(b * H_ + h) * HD) + d) * LP + l] = tile[dr][chunk + i];
            }
        }
    }
}

// -------------------------------------------------------------------------
// Flash attention, bf16 MFMA, split-K x2 (additive merge).
// Cooperative LDS staging of K/V tiles (4 waves share one copy, 4x less
// vmem), software-pipelined: next K/V tile in registers, next rpe in
// registers, while current kt computes. Masking folded into rpe values.
// grid 2048: bid = b(2) | ks(1) | h(3) | rt(5), b fastest for rpe L3 reuse.
// -------------------------------------------------------------------------
__global__ __launch_bounds__(256) void attn_mfma(
    const unsigned short* __restrict__ Q, const unsigned short* __restrict__ K,
    const unsigned short* __restrict__ Vt, const float* __restrict__ rpe,
    float* __restrict__ po, float* __restrict__ lsum) {
    __shared__ __align__(16) unsigned short Ks[64][72];
    __shared__ __align__(16) unsigned short Vs[64][72];
    __shared__ __align__(16) unsigned short Ps[4][16][72];
    const int lane = threadIdx.x & 63;
    const int wave = threadIdx.x >> 6;
    const int c = lane & 15;
    const int quad = lane >> 4;
    const int bid = blockIdx.x;
    const int b  = bid & 3;
    const int ks = (bid >> 2) & 1;
    const int h  = (bid >> 3) & 7;
    const int rt = bid >> 6;
    const int r0 = rt * 64 + wave * 16;
    const int bh = b * H_ + h;
    const unsigned short* Qb = Q + (size_t)bh * LP * HD;
    const unsigned short* Kb = K + (size_t)bh * LP * HD;
    const unsigned short* Vb = Vt + (size_t)bh * HD * LP;
    const float* rb = rpe + (size_t)h * L_ * L_;

    // staging coords: wave stages rows [wave*16, wave*16+16) of the 64-tile
    const int srow = wave * 16 + (lane >> 3);   // +0 / +8 per issue
    const int scol = (lane & 7) * 8;            // shorts
    const unsigned short* Kst = Kb + (size_t)srow * HD + scol;
    const unsigned short* Vst = Vb + (size_t)srow * LP + scol;

    bf16x8 qf0 = *(const bf16x8*)&Qb[(size_t)(r0 + c) * HD + quad * 8];
    bf16x8 qf1 = *(const bf16x8*)&Qb[(size_t)(r0 + c) * HD + 32 + quad * 8];

    float l_i[4] = {0.f, 0.f, 0.f, 0.f};
    f32x4 o_acc[4] = {{0,0,0,0},{0,0,0,0},{0,0,0,0},{0,0,0,0}};
    const int rg0 = r0 + quad * 4;

    const int kt0 = ks * 16, kt_end = kt0 + 16;

    // ---- prologue: stage regs + rpe for first kt ----
    uint4 kreg[2], vreg[2];
    float rp[4][4];
    {
        const int c0 = kt0 * 64;
        kreg[0] = *(const uint4*)(Kst + (size_t)c0 * HD);
        kreg[1] = *(const uint4*)(Kst + (size_t)c0 * HD + 8 * HD);
        vreg[0] = *(const uint4*)(Vst + c0);
        vreg[1] = *(const uint4*)(Vst + c0 + 8 * LP);
        const bool edge = (rt == 31);   // kt0 is never 31
#pragma unroll
        for (int r = 0; r < 4; r++) {
            int rg = rg0 + r;
#pragma unroll
            for (int t = 0; t < 4; t++) {
                int col = c0 + 16 * t + c;
                if (!edge) {
                    rp[r][t] = rb[(size_t)rg * L_ + col];
                } else {
                    float raw = rb[(size_t)min(rg, L_ - 1) * L_ + col];
                    rp[r][t] = (rg < L_) ? raw : 0.f;
                }
            }
        }
    }

    for (int kt = kt0; kt < kt_end; kt++) {
        __syncthreads();   // all waves done reading Ks/Vs of previous iter
        *(uint4*)&Ks[srow][scol]     = kreg[0];
        *(uint4*)&Ks[srow + 8][scol] = kreg[1];
        *(uint4*)&Vs[srow][scol]     = vreg[0];
        *(uint4*)&Vs[srow + 8][scol] = vreg[1];
        __syncthreads();   // staged tile visible

        // issue next tile's global loads (consumed next iteration)
        if (kt + 1 < kt_end) {
            const int c1 = (kt + 1) * 64;
            kreg[0] = *(const uint4*)(Kst + (size_t)c1 * HD);
            kreg[1] = *(const uint4*)(Kst + (size_t)c1 * HD + 8 * HD);
            vreg[0] = *(const uint4*)(Vst + c1);
            vreg[1] = *(const uint4*)(Vst + c1 + 8 * LP);
        }

        // ---- S = Q K^T from LDS ----
        f32x4 s[4];
#pragma unroll
        for (int t = 0; t < 4; t++) {
            bf16x8 k0f = *(const bf16x8*)&Ks[16 * t + c][quad * 8];
            bf16x8 k1f = *(const bf16x8*)&Ks[16 * t + c][32 + quad * 8];
            f32x4 z = {0, 0, 0, 0};
            z = __builtin_amdgcn_mfma_f32_16x16x32_bf16(qf0, k0f, z, 0, 0, 0);
            z = __builtin_amdgcn_mfma_f32_16x16x32_bf16(qf1, k1f, z, 0, 0, 0);
            s[t] = z;
        }

        // ---- prefetch next kt's rpe (masking folded in) ----
        float rpn[4][4];
        if (kt + 1 < kt_end) {
            const int c1 = (kt + 1) * 64;
            const bool edge = (rt == 31) || (kt + 1 == 31);
#pragma unroll
            for (int r = 0; r < 4; r++) {
                int rg = rg0 + r;
#pragma unroll
                for (int t = 0; t < 4; t++) {
                    int col = c1 + 16 * t + c;
                    if (!edge) {
                        rpn[r][t] = rb[(size_t)rg * L_ + col];
                    } else {
                        float raw = rb[(size_t)min(rg, L_ - 1) * L_ + min(col, L_ - 1)];
                        rpn[r][t] = (col >= L_) ? -1e30f : ((rg < L_) ? raw : 0.f);
                    }
                }
            }
        }

        // ---- exp + Ps + lane-local l ----
#pragma unroll
        for (int r = 0; r < 4; r++) {
            float psum = 0.f;
#pragma unroll
            for (int t = 0; t < 4; t++) {
                float p = __expf(s[t][r] * 0.125f + rp[r][t]);
                psum += p;
                Ps[wave][quad * 4 + r][16 * t + c] = f2bf(p);
            }
            l_i[r] += psum;
        }

        // ---- O += P V from LDS (Ps is per-wave: no barrier needed) ----
        bf16x8 pa0 = *(const bf16x8*)&Ps[wave][c][quad * 8];
        bf16x8 pa1 = *(const bf16x8*)&Ps[wave][c][32 + quad * 8];
#pragma unroll
        for (int t = 0; t < 4; t++) {
            bf16x8 v0 = *(const bf16x8*)&Vs[16 * t + c][quad * 8];
            bf16x8 v1 = *(const bf16x8*)&Vs[16 * t + c][32 + quad * 8];
            o_acc[t] = __builtin_amdgcn_mfma_f32_16x16x32_bf16(pa0, v0, o_acc[t], 0, 0, 0);
            o_acc[t] = __builtin_amdgcn_mfma_f32_16x16x32_bf16(pa1, v1, o_acc[t], 0, 0, 0);
        }

#pragma unroll
        for (int r = 0; r < 4; r++)
#pragma unroll
            for (int t = 0; t < 4; t++) rp[r][t] = rpn[r][t];
    }

    // ---- epilogue ----
#pragma unroll
    for (int r = 0; r < 4; r++) {
        float v = l_i[r];
        v += __shfl_xor(v, 1);
        v += __shfl_xor(v, 2);
        v += __shfl_xor(v, 4);
        v += __shfl_xor(v, 8);
        l_i[r] = v;
    }
    float* pob = po + (size_t)(ks * 32 + bh) * L_ * HD;
#pragma unroll
    for (int t = 0; t < 4; t++) {
        int d = 16 * t + c;
#pragma unroll
        for (int r = 0; r < 4; r++) {
            int l = rg0 + r;
            if (l < L_) pob[(size_t)l * HD + d] = o_acc[t][r];
        }
    }
    if (c == 0) {
        float* lb = lsum + (size_t)(ks * 32 + bh) * LP;
#pragma unroll
        for (int r = 0; r < 4; r++) lb[rg0 + r] = l_i[r];
    }
}

// -------------------------------------------------------------------------
// Merge: out[bh][d][l] = (po0+po1)[bh][l][d] / (l0+l1)[bh][l], LDS transpose.
// -------------------------------------------------------------------------
__global__ __launch_bounds__(256) void merge_kernel(
    const float* __restrict__ po, const float* __restrict__ lsum,
    float* __restrict__ out) {
    __shared__ __align__(16) float T[64][68];
    const int tid = threadIdx.x;
    const int bh = blockIdx.x >> 5;
    const int lt = blockIdx.x & 31;
    const float* p0 = po + (size_t)bh * L_ * HD;
    const float* p1 = p0 + (size_t)32 * L_ * HD;
    const float* ls0 = lsum + (size_t)bh * LP;
    const float* ls1 = ls0 + (size_t)32 * LP;
#pragma unroll
    for (int it = 0; it < 4; it++) {
        int idx = it * 256 + tid;
        int row = idx >> 4;
        int dc = (idx & 15) * 4;
        int l = lt * 64 + row;
        float4 v = make_float4(0.f, 0.f, 0.f, 0.f);
        if (l < L_) {
            float4 a  = *(const float4*)&p0[(size_t)l * HD + dc];
            float4 b4 = *(const float4*)&p1[(size_t)l * HD + dc];
            float inv = 1.f / (ls0[l] + ls1[l]);
            v = make_float4((a.x + b4.x) * inv, (a.y + b4.y) * inv,
                            (a.z + b4.z) * inv, (a.w + b4.w) * inv);
        }
        T[dc + 0][row] = v.x; T[dc + 1][row] = v.y;
        T[dc + 2][row] = v.z; T[dc + 3][row] = v.w;
    }
    __syncthreads();
    const int d = tid >> 2, ch = (tid & 3) * 16;
    const int lbase = lt * 64 + ch;
    if (lbase + 15 < L_) {
        float* dst = &out[((size_t)(bh * HD + d)) * L_ + lbase];
#pragma unroll
        for (int i = 0; i < 4; i++)
            *(float4*)&dst[4 * i] = *(const float4*)&T[d][ch + 4 * i];
    }
}

extern "C" void kernel_launch(void* const* d_in, const int* in_sizes, int n_in,
                              void* d_out, int out_size, void* d_ws, size_t ws_size,
                              hipStream_t stream) {
    const float* x   = (const float*)d_in[0];
    const float* rpe = (const float*)d_in[1];
    const float* Wq  = (const float*)d_in[2];
    const float* bq  = (const float*)d_in[3];
    const float* Wkv = (const float*)d_in[4];
    const float* bkv = (const float*)d_in[5];
    const float* Wl  = (const float*)d_in[6];
    const float* bl  = (const float*)d_in[7];
    float* out = (float*)d_out;

    unsigned short* wsu  = (unsigned short*)d_ws;
    unsigned short* x16  = wsu;                 // 4,096,000
    unsigned short* kv16 = wsu + 4096000;       // 4,096,000
    unsigned short* Wq16 = wsu + 8192000;       //   262,144
    unsigned short* Wkv16= wsu + 8454144;       //   524,288
    unsigned short* Q16  = wsu + 8978432;       // 4,194,304  [bh][2048][64]
    unsigned short* K16  = wsu + 13172736;      // 4,194,304  [bh][2048][64]
    unsigned short* V16  = wsu + 17367040;      // 4,194,304  [bh][64][2048]
    float* po   = (float*)(wsu + 21561344);     // 8,192,000 fp32 [2][32][2000][64]
    float* lsum = po + 8192000;                 //   131,072 fp32 [2][32][2048]

    conv_kernel<<<(B_ * L_ * C_ / 4 + 255) / 256, 256, 0, stream>>>(x, Wl, bl, kv16, x16);
    cvt_kernel<<<(786432 / 4 + 255) / 256, 256, 0, stream>>>(Wq, Wkv, Wq16, Wkv16);
    proj_mfma<<<dim3(125, 8), 256, 0, stream>>>(x16, Wq16, bq, Q16, nullptr, 0);
    proj_mfma<<<dim3(125, 16), 256, 0, stream>>>(kv16, Wkv16, bkv, K16, V16, 1);
    attn_mfma<<<2048, 256, 0, stream>>>(Q16, K16, V16, rpe, po, lsum);
    merge_kernel<<<1024, 256, 0, stream>>>(po, lsum, out);
}

// Round 5
// 535.788 us; speedup vs baseline: 1.4253x; 1.1562x over previous
//
#include <hip/hip_runtime.h>

#define B_ 4
#define L_ 2000
#define LP 2048       // padded length for Q/K/V buffers
#define C_ 512
#define H_ 8
#define HD 64
#define CHUNK_ 1000

typedef __attribute__((ext_vector_type(8))) short bf16x8;
typedef __attribute__((ext_vector_type(4))) float f32x4;

__device__ inline unsigned short f2bf(float f) {
    union { float f; unsigned int u; } v; v.f = f;
    unsigned int r = v.u + 0x7fffu + ((v.u >> 16) & 1u);
    return (unsigned short)(r >> 16);
}

// -------------------------------------------------------------------------
// conv (depthwise k=3, zero pad at 1000-chunk boundaries) + residual + bias,
// bf16 out; also emits x cast to bf16. Vectorized x4 over channels.
// -------------------------------------------------------------------------
__global__ void conv_kernel(const float* __restrict__ x, const float* __restrict__ Wl,
                            const float* __restrict__ bl,
                            unsigned short* __restrict__ kv16,
                            unsigned short* __restrict__ x16) {
    int i4 = blockIdx.x * 256 + threadIdx.x;
    if (i4 >= B_ * L_ * C_ / 4) return;
    int idx = i4 * 4;
    int c = idx & (C_ - 1);
    int l = (idx >> 9) % L_;
    int p = l % CHUNK_;
    float4 xc = *(const float4*)&x[idx];
    float4 lf = (p > 0)          ? *(const float4*)&x[idx - C_] : make_float4(0, 0, 0, 0);
    float4 rt = (p < CHUNK_ - 1) ? *(const float4*)&x[idx + C_] : make_float4(0, 0, 0, 0);
    float y[4];
    const float* xcp = &xc.x; const float* lfp = &lf.x; const float* rtp = &rt.x;
#pragma unroll
    for (int j = 0; j < 4; j++) {
        y[j] = xcp[j] + bl[c + j] + Wl[(c + j) * 3 + 0] * lfp[j]
             + Wl[(c + j) * 3 + 1] * xcp[j] + Wl[(c + j) * 3 + 2] * rtp[j];
    }
    ushort4 kv = make_ushort4(f2bf(y[0]), f2bf(y[1]), f2bf(y[2]), f2bf(y[3]));
    ushort4 xo = make_ushort4(f2bf(xcp[0]), f2bf(xcp[1]), f2bf(xcp[2]), f2bf(xcp[3]));
    *(ushort4*)&kv16[idx] = kv;
    *(ushort4*)&x16[idx]  = xo;
}

// Both weight tensors cast in one launch (x4 vectorized).
__global__ void cvt_kernel(const float* __restrict__ Wq, const float* __restrict__ Wkv,
                           unsigned short* __restrict__ Wq16,
                           unsigned short* __restrict__ Wkv16) {
    int i4 = blockIdx.x * 256 + threadIdx.x;
    int idx = i4 * 4;
    const float* src; unsigned short* dst; int off;
    if (idx < 262144) { src = Wq; dst = Wq16; off = idx; }
    else if (idx < 786432) { src = Wkv; dst = Wkv16; off = idx - 262144; }
    else return;
    float4 v = *(const float4*)&src[off];
    *(ushort4*)&dst[off] = make_ushort4(f2bf(v.x), f2bf(v.y), f2bf(v.z), f2bf(v.w));
}

// -------------------------------------------------------------------------
// Projection GEMM via MFMA, LDS-staged coalesced epilogue.
// A:[8000][512] bf16, W:[N][512] bf16. Block: 4 waves, 64m x 64n tile.
// mode 0: Q -> [bh][2048][64]. mode 1: by<8 -> K [bh][2048][64];
//         by>=8 -> V transposed [bh][64][2048] (LDS transpose, row stores).
// -------------------------------------------------------------------------
__global__ __launch_bounds__(256) void proj_mfma(
    const unsigned short* __restrict__ A, const unsigned short* __restrict__ W,
    const float* __restrict__ bias,
    unsigned short* __restrict__ o0, unsigned short* __restrict__ o1, int mode) {
    __shared__ __align__(16) unsigned short tile[64][72];
    const int tid = threadIdx.x;
    const int lane = tid & 63;
    const int wave = tid >> 6;
    const int c = lane & 15;
    const int quad = lane >> 4;
    const int mrow = blockIdx.x * 64 + wave * 16 + c;
    const int n0 = blockIdx.y * 64;
    f32x4 acc[4] = {{0,0,0,0},{0,0,0,0},{0,0,0,0},{0,0,0,0}};
    const unsigned short* Ap = A + (size_t)mrow * C_ + quad * 8;
#pragma unroll 4
    for (int k0 = 0; k0 < C_; k0 += 32) {
        bf16x8 a = *(const bf16x8*)(Ap + k0);
#pragma unroll
        for (int t = 0; t < 4; t++) {
            bf16x8 wv = *(const bf16x8*)&W[(size_t)(n0 + 16 * t + c) * C_ + k0 + quad * 8];
            acc[t] = __builtin_amdgcn_mfma_f32_16x16x32_bf16(a, wv, acc[t], 0, 0, 0);
        }
    }
    const bool vpath = (mode == 1 && n0 >= C_);
    const int lm = wave * 16 + quad * 4;
#pragma unroll
    for (int t = 0; t < 4; t++) {
        float bv = bias[n0 + 16 * t + c];
#pragma unroll
        for (int r = 0; r < 4; r++) {
            unsigned short val = f2bf(acc[t][r] + bv);
            if (!vpath) tile[lm + r][16 * t + c] = val;   // [m][n]
            else        tile[16 * t + c][lm + r] = val;   // [n][m] transpose
        }
    }
    __syncthreads();
    if (!vpath) {
        int lr = tid >> 2, chunk = (tid & 3) * 16;
        int m = blockIdx.x * 64 + lr;
        int b = m / L_, l = m % L_;
        int nn = (n0 + chunk) & (C_ - 1);
        int h = nn >> 6, d0 = nn & 63;
        unsigned short* dst = &o0[(((size_t)(b * H_ + h) * LP) + l) * HD + d0];
        *(uint4*)dst       = *(const uint4*)&tile[lr][chunk];
        *(uint4*)(dst + 8) = *(const uint4*)&tile[lr][chunk + 8];
    } else {
        int dr = tid >> 2, chunk = (tid & 3) * 16;
        int nn = (n0 - C_) + dr;
        int h = nn >> 6, d = nn & 63;
        int mbase = blockIdx.x * 64 + chunk;
        int b0 = mbase / L_, b1 = (mbase + 15) / L_;
        if (b0 == b1) {
            int l = mbase % L_;
            unsigned short* dst = &o1[(((size_t)(b0 * H_ + h) * HD) + d) * LP + l];
            *(uint4*)dst       = *(const uint4*)&tile[dr][chunk];
            *(uint4*)(dst + 8) = *(const uint4*)&tile[dr][chunk + 8];
        } else {
            for (int i = 0; i < 16; i++) {
                int m = mbase + i;
                int b = m / L_, l = m % L_;
                o1[(((size_t)(b * H_ + h) * HD) + d) * LP + l] = tile[dr][chunk + i];
            }
        }
    }
}

// -------------------------------------------------------------------------
// Flash attention, bf16 MFMA. ONE BLOCK = ALL 4 BATCHES of (h, 64-row tile,
// K-half): rpe is loaded once and shared across b (each rpe byte read
// exactly once from HBM kernel-wide); K/V tiles (32 cols) staged in LDS
// shared by 4 waves; 4 independent per-batch chains per iteration give ILP.
// Register budget via __launch_bounds__(256,2): NO spills (the round-3/4
// failure). Grid 512 = exactly 2 blocks/CU, single generation.
// -------------------------------------------------------------------------
__global__ __launch_bounds__(256, 2) void attn_mfma(
    const unsigned short* __restrict__ Q, const unsigned short* __restrict__ K,
    const unsigned short* __restrict__ Vt, const float* __restrict__ rpe,
    float* __restrict__ po, float* __restrict__ lsum) {
    __shared__ __align__(16) unsigned short Ks[4][32][72];   // [b][s-col][k=64+pad]
    __shared__ __align__(16) unsigned short Vs[4][64][40];   // [b][d][l=32+pad]
    __shared__ __align__(16) unsigned short Ps[4][2][16][72];// [wave][b&1][row][col]
    const int tid = threadIdx.x;
    const int lane = tid & 63;
    const int wave = tid >> 6;
    const int c = lane & 15;
    const int quad = lane >> 4;
    const int bid = blockIdx.x;
    const int ks = bid & 1;
    const int h  = (bid >> 1) & 7;
    const int rt = bid >> 4;
    const int r0w = rt * 64 + wave * 16;
    const int rg0 = r0w + quad * 4;
    const float* rb = rpe + (size_t)h * L_ * L_;

    // staging coords: K tile [32 rows][64 k] (128B rows), V tile [64 d][32 l]
    const int krow = tid >> 3, kcol = (tid & 7) * 8;
    const int vrow = tid >> 2, vcol = (tid & 3) * 8;

    bf16x8 qf0[4], qf1[4];
    const unsigned short* Kst[4];
    const unsigned short* Vst[4];
#pragma unroll
    for (int b = 0; b < 4; b++) {
        const unsigned short* Qb = Q + (size_t)(b * H_ + h) * LP * HD;
        qf0[b] = *(const bf16x8*)&Qb[(size_t)(r0w + c) * HD + quad * 8];
        qf1[b] = *(const bf16x8*)&Qb[(size_t)(r0w + c) * HD + 32 + quad * 8];
        Kst[b] = K  + (size_t)(b * H_ + h) * LP * HD + (size_t)krow * HD + kcol;
        Vst[b] = Vt + (size_t)(b * H_ + h) * HD * LP + (size_t)vrow * LP + vcol;
    }

    float l_i[4][4] = {};
    f32x4 o_acc[4][4];
#pragma unroll
    for (int b = 0; b < 4; b++)
#pragma unroll
        for (int t = 0; t < 4; t++) o_acc[b][t] = (f32x4){0.f, 0.f, 0.f, 0.f};

    const int kt0 = ks * 32, kt1 = kt0 + 32;

    // ---- prologue: prefetch first K/V tiles + rpe (pre-scaled by log2e) ----
    uint4 kpre[4], vpre[4];
    float rpl[4][2];
    {
        const int c0 = kt0 * 32;
#pragma unroll
        for (int b = 0; b < 4; b++) {
            kpre[b] = *(const uint4*)(Kst[b] + (size_t)c0 * HD);
            vpre[b] = *(const uint4*)(Vst[b] + c0);
        }
        const bool redge = (rt == 31);   // first tile never has col edge
#pragma unroll
        for (int r = 0; r < 4; r++) {
            const int rg = rg0 + r;
            const int rgc = redge ? min(rg, L_ - 1) : rg;
#pragma unroll
            for (int t = 0; t < 2; t++) {
                float raw = rb[(size_t)rgc * L_ + c0 + 16 * t + c];
                rpl[r][t] = (!redge || rg < L_) ? raw * 1.44269504f : 0.f;
            }
        }
    }

    for (int kt = kt0; kt < kt1; kt++) {
        __syncthreads();   // all waves done with previous tiles
#pragma unroll
        for (int b = 0; b < 4; b++) {
            *(uint4*)&Ks[b][krow][kcol] = kpre[b];
            *(uint4*)&Vs[b][vrow][vcol] = vpre[b];
        }
        __syncthreads();   // tiles visible

        // prefetch next K/V tiles (consumed next iteration)
        if (kt + 1 < kt1) {
            const int c1 = (kt + 1) * 32;
#pragma unroll
            for (int b = 0; b < 4; b++) {
                kpre[b] = *(const uint4*)(Kst[b] + (size_t)c1 * HD);
                vpre[b] = *(const uint4*)(Vst[b] + c1);
            }
        }
        // prefetch next rpe (masking + log2e folded in)
        float rpn[4][2];
        if (kt + 1 < kt1) {
            const int c1 = (kt + 1) * 32;
            const bool edge = (rt == 31) || (kt + 1 >= 62);
            if (!edge) {
#pragma unroll
                for (int r = 0; r < 4; r++)
#pragma unroll
                    for (int t = 0; t < 2; t++)
                        rpn[r][t] = rb[(size_t)(rg0 + r) * L_ + c1 + 16 * t + c]
                                    * 1.44269504f;
            } else {
#pragma unroll
                for (int r = 0; r < 4; r++) {
                    const int rg = rg0 + r;
                    const int rgc = min(rg, L_ - 1);
#pragma unroll
                    for (int t = 0; t < 2; t++) {
                        const int col = c1 + 16 * t + c;
                        float raw = rb[(size_t)rgc * L_ + min(col, L_ - 1)];
                        rpn[r][t] = (col >= L_) ? -1e30f
                                   : ((rg < L_) ? raw * 1.44269504f : 0.f);
                    }
                }
            }
        }

        // ---- 4 independent per-batch chains (ILP) ----
#pragma unroll
        for (int b = 0; b < 4; b++) {
            // S = Q K^T : 16x32 tile, K-dim 64
            f32x4 s[2];
#pragma unroll
            for (int t = 0; t < 2; t++) {
                bf16x8 k0f = *(const bf16x8*)&Ks[b][16 * t + c][quad * 8];
                bf16x8 k1f = *(const bf16x8*)&Ks[b][16 * t + c][32 + quad * 8];
                f32x4 z = {0.f, 0.f, 0.f, 0.f};
                z = __builtin_amdgcn_mfma_f32_16x16x32_bf16(qf0[b], k0f, z, 0, 0, 0);
                z = __builtin_amdgcn_mfma_f32_16x16x32_bf16(qf1[b], k1f, z, 0, 0, 0);
                s[t] = z;
            }
            // p = exp2(s*scale*log2e + rpe*log2e); lane-local l; P -> LDS
#pragma unroll
            for (int r = 0; r < 4; r++) {
                float psum = 0.f;
#pragma unroll
                for (int t = 0; t < 2; t++) {
                    float p = exp2f(fmaf(s[t][r], 0.18033688f, rpl[r][t]));
                    psum += p;
                    Ps[wave][b & 1][quad * 4 + r][16 * t + c] = f2bf(p);
                }
                l_i[b][r] += psum;
            }
            // O += P V : K-dim 32, one MFMA per d-tile
            bf16x8 pa = *(const bf16x8*)&Ps[wave][b & 1][c][quad * 8];
#pragma unroll
            for (int t = 0; t < 4; t++) {
                bf16x8 v0 = *(const bf16x8*)&Vs[b][16 * t + c][quad * 8];
                o_acc[b][t] = __builtin_amdgcn_mfma_f32_16x16x32_bf16(pa, v0, o_acc[b][t], 0, 0, 0);
            }
        }
        if (kt + 1 < kt1) {
#pragma unroll
            for (int r = 0; r < 4; r++) { rpl[r][0] = rpn[r][0]; rpl[r][1] = rpn[r][1]; }
        }
    }

    // ---- epilogue: reduce l over 16 c-lanes; store raw partials ----
#pragma unroll
    for (int b = 0; b < 4; b++) {
#pragma unroll
        for (int r = 0; r < 4; r++) {
            float v = l_i[b][r];
            v += __shfl_xor(v, 1);
            v += __shfl_xor(v, 2);
            v += __shfl_xor(v, 4);
            v += __shfl_xor(v, 8);
            l_i[b][r] = v;
        }
        float* pob = po + (size_t)(ks * 32 + b * H_ + h) * L_ * HD;
#pragma unroll
        for (int t = 0; t < 4; t++) {
            int d = 16 * t + c;
#pragma unroll
            for (int r = 0; r < 4; r++) {
                int l = rg0 + r;
                if (l < L_) pob[(size_t)l * HD + d] = o_acc[b][t][r];
            }
        }
        if (c == 0) {
            float* lb = lsum + (size_t)(ks * 32 + b * H_ + h) * LP;
#pragma unroll
            for (int r = 0; r < 4; r++) lb[rg0 + r] = l_i[b][r];
        }
    }
}

// -------------------------------------------------------------------------
// Merge: out[bh][d][l] = (po0+po1)[bh][l][d] / (l0+l1)[bh][l], LDS transpose.
// -------------------------------------------------------------------------
__global__ __launch_bounds__(256) void merge_kernel(
    const float* __restrict__ po, const float* __restrict__ lsum,
    float* __restrict__ out) {
    __shared__ __align__(16) float T[64][68];
    const int tid = threadIdx.x;
    const int bh = blockIdx.x >> 5;
    const int lt = blockIdx.x & 31;
    const float* p0 = po + (size_t)bh * L_ * HD;
    const float* p1 = p0 + (size_t)32 * L_ * HD;
    const float* ls0 = lsum + (size_t)bh * LP;
    const float* ls1 = ls0 + (size_t)32 * LP;
#pragma unroll
    for (int it = 0; it < 4; it++) {
        int idx = it * 256 + tid;
        int row = idx >> 4;
        int dc = (idx & 15) * 4;
        int l = lt * 64 + row;
        float4 v = make_float4(0.f, 0.f, 0.f, 0.f);
        if (l < L_) {
            float4 a  = *(const float4*)&p0[(size_t)l * HD + dc];
            float4 b4 = *(const float4*)&p1[(size_t)l * HD + dc];
            float inv = 1.f / (ls0[l] + ls1[l]);
            v = make_float4((a.x + b4.x) * inv, (a.y + b4.y) * inv,
                            (a.z + b4.z) * inv, (a.w + b4.w) * inv);
        }
        T[dc + 0][row] = v.x; T[dc + 1][row] = v.y;
        T[dc + 2][row] = v.z; T[dc + 3][row] = v.w;
    }
    __syncthreads();
    const int d = tid >> 2, ch = (tid & 3) * 16;
    const int lbase = lt * 64 + ch;
    if (lbase + 15 < L_) {
        float* dst = &out[((size_t)(bh * HD + d)) * L_ + lbase];
#pragma unroll
        for (int i = 0; i < 4; i++)
            *(float4*)&dst[4 * i] = *(const float4*)&T[d][ch + 4 * i];
    }
}

extern "C" void kernel_launch(void* const* d_in, const int* in_sizes, int n_in,
                              void* d_out, int out_size, void* d_ws, size_t ws_size,
                              hipStream_t stream) {
    const float* x   = (const float*)d_in[0];
    const float* rpe = (const float*)d_in[1];
    const float* Wq  = (const float*)d_in[2];
    const float* bq  = (const float*)d_in[3];
    const float* Wkv = (const float*)d_in[4];
    const float* bkv = (const float*)d_in[5];
    const float* Wl  = (const float*)d_in[6];
    const float* bl  = (const float*)d_in[7];
    float* out = (float*)d_out;

    unsigned short* wsu  = (unsigned short*)d_ws;
    unsigned short* x16  = wsu;                 // 4,096,000
    unsigned short* kv16 = wsu + 4096000;       // 4,096,000
    unsigned short* Wq16 = wsu + 8192000;       //   262,144
    unsigned short* Wkv16= wsu + 8454144;       //   524,288
    unsigned short* Q16  = wsu + 8978432;       // 4,194,304  [bh][2048][64]
    unsigned short* K16  = wsu + 13172736;      // 4,194,304  [bh][2048][64]
    unsigned short* V16  = wsu + 17367040;      // 4,194,304  [bh][64][2048]
    float* po   = (float*)(wsu + 21561344);     // 8,192,000 fp32 [2][32][2000][64]
    float* lsum = po + 8192000;                 //   131,072 fp32 [2][32][2048]

    conv_kernel<<<(B_ * L_ * C_ / 4 + 255) / 256, 256, 0, stream>>>(x, Wl, bl, kv16, x16);
    cvt_kernel<<<(786432 / 4 + 255) / 256, 256, 0, stream>>>(Wq, Wkv, Wq16, Wkv16);
    proj_mfma<<<dim3(125, 8), 256, 0, stream>>>(x16, Wq16, bq, Q16, nullptr, 0);
    proj_mfma<<<dim3(125, 16), 256, 0, stream>>>(kv16, Wkv16, bkv, K16, V16, 1);
    attn_mfma<<<512, 256, 0, stream>>>(Q16, K16, V16, rpe, po, lsum);
    merge_kernel<<<1024, 256, 0, stream>>>(po, lsum, out);
}